// Round 13
// baseline (122.284 us; speedup 1.0000x reference)
//
#include <hip/hip_runtime.h>
#include <math.h>

#define C_NUM 1000
#define M_MODES 10
#define D_FEAT 128
#define N_BATCH 1024

typedef _Float16 h16;
typedef h16 h16x2 __attribute__((ext_vector_type(2)));
typedef h16 half8 __attribute__((ext_vector_type(8)));
typedef float f32x4 __attribute__((ext_vector_type(4)));

// ---- workspace layout (float units) ----
#define OFF_FEATH  0              // h16[1024*128] (only workspace user now)

// ---------------- feat fp32 -> fp16 (trivial, latency-free) ------------------
__global__ __launch_bounds__(256) void feat_cvt(
    const float* __restrict__ feat, h16* __restrict__ feat_h)
{
    const int n    = blockIdx.x * 4 + (threadIdx.x >> 6);
    const int lane = threadIdx.x & 63;
    float2 f = ((const float2*)feat)[n * 64 + lane];
    ((h16x2*)(feat_h + n * D_FEAT))[lane] = (h16x2){(h16)f.x, (h16)f.y};
}

// ---------------- K3': fully fused GEMM + in-block prep ----------------------
// block tile: 128 n x 80 cm (8 whole classes); 8 waves.
// Wave w preps class (blockIdx.x*8+w) IN-BLOCK: prototypes, label scan,
// softmax/CV, kappa, cmc -> LDS. B tile (updated normalized fp16 prototypes)
// is written directly to LDS; no ave_h/cmc global round-trip. Prep latency
// hides under A-staging and co-resident blocks' MFMA.
// LDS: A 32KB swz | B 20KB swz | cmc SoA 6x80 f32. ls overlay after barrier.
#define SWZ(row, j) (((row) << 8) + ((((j) ^ ((row) & 15))) << 4))
#define LSTR 81
__global__ __launch_bounds__(512, 4) void k3_fused(
    const h16*   __restrict__ feat_h,    // [1024][128] fp16
    const float* __restrict__ feat,      // [1024][128] fp32
    const float* __restrict__ ave_old,   // [1000][10][128]
    const float* __restrict__ amount,    // [10000]
    const int*   __restrict__ labels,    // [1024]
    float* __restrict__ out)             // [1024][1000]
{
    __shared__ __align__(16) char smem[128 * 256 + 80 * 256 + 6 * 80 * 4];
    char*  smemB = smem + 128 * 256;
    float* cmcs  = (float*)(smem + 128 * 256 + 80 * 256);  // [6][80] SoA
    float* ls    = (float*)smem;          // [128][81] overlay (41472 B)

    const int tid    = threadIdx.x;
    const int wave   = tid >> 6;          // 0..7
    const int lane   = tid & 63;
    const int cmbase = blockIdx.x * 80;   // 125 x-tiles
    const int nbase  = blockIdx.y * 128;  // 8 y-tiles
    const int cls    = blockIdx.x * 8 + wave;   // class this wave preps

    const float2* feat2 = (const float2*)feat;
    const float2* ave2  = (const float2*)ave_old;

    // ---- issue prototype loads FIRST (prep-critical), then A-tile loads ----
    float2 ao[M_MODES];
    #pragma unroll
    for (int t = 0; t < M_MODES; ++t) ao[t] = ave2[(cls * M_MODES + t) * 64 + lane];

    float4 av0, av1, av2_, av3;
    {
        const float4* src = (const float4*)(feat_h + nbase * D_FEAT);
        av0 = src[tid]; av1 = src[tid + 512]; av2_ = src[tid + 1024]; av3 = src[tid + 1536];
    }

    // ---- prototype norms (waits only on ao; A loads stay in flight) ----
    float an[M_MODES];
    #pragma unroll
    for (int t = 0; t < M_MODES; ++t) an[t] = ao[t].x * ao[t].x + ao[t].y * ao[t].y;
    #pragma unroll
    for (int s = 1; s < 64; s <<= 1)
        #pragma unroll
        for (int t = 0; t < M_MODES; ++t) an[t] += __shfl_xor(an[t], s);
    #pragma unroll
    for (int t = 0; t < M_MODES; ++t) an[t] = sqrtf(an[t]);

    // ---- stage A (drains A loads; latency was hidden by norm butterfly) ----
    {
        int e, r, j;
        e = tid;        r = e >> 4; j = e & 15; *(float4*)(smem + SWZ(r, j)) = av0;
        e = tid + 512;  r = e >> 4; j = e & 15; *(float4*)(smem + SWZ(r, j)) = av1;
        e = tid + 1024; r = e >> 4; j = e & 15; *(float4*)(smem + SWZ(r, j)) = av2_;
        e = tid + 1536; r = e >> 4; j = e & 15; *(float4*)(smem + SWZ(r, j)) = av3;
    }

    // ---- label scan + per-sample softmax/CV accumulation for class cls ----
    float ssum[M_MODES], wx[M_MODES], wy[M_MODES];
    #pragma unroll
    for (int t = 0; t < M_MODES; ++t) { ssum[t] = 0.f; wx[t] = 0.f; wy[t] = 0.f; }

    const int4* lab4 = (const int4*)labels;
    #pragma unroll 1
    for (int k4 = 0; k4 < 4; ++k4) {
        int4 lv = lab4[lane + k4 * 64];
        #pragma unroll
        for (int j = 0; j < 4; ++j) {
            int lbl = (j == 0) ? lv.x : (j == 1) ? lv.y : (j == 2) ? lv.z : lv.w;
            unsigned long long mask = __ballot(lbl == cls);
            while (mask) {
                int lz = __ffsll((long long)mask) - 1;
                mask &= mask - 1;
                const int n = 4 * lz + 256 * k4 + j;
                float2 f = feat2[n * 64 + lane];
                float d[M_MODES], fn = f.x * f.x + f.y * f.y;
                #pragma unroll
                for (int t = 0; t < M_MODES; ++t)
                    d[t] = f.x * ao[t].x + f.y * ao[t].y;
                #pragma unroll
                for (int s = 1; s < 64; s <<= 1) {
                    fn += __shfl_xor(fn, s);
                    #pragma unroll
                    for (int t = 0; t < M_MODES; ++t) d[t] += __shfl_xor(d[t], s);
                }
                const float fnorm = sqrtf(fn);
                float sc[M_MODES], mx = -INFINITY;
                #pragma unroll
                for (int t = 0; t < M_MODES; ++t) {
                    float den = fmaxf(fnorm * an[t], 1e-8f);
                    sc[t] = d[t] / den;
                    mx = fmaxf(mx, sc[t]);
                }
                float se = 0.f;
                #pragma unroll
                for (int t = 0; t < M_MODES; ++t) { sc[t] = __expf(sc[t] - mx); se += sc[t]; }
                const float inv = 1.0f / se;
                #pragma unroll
                for (int t = 0; t < M_MODES; ++t) {
                    float sm = sc[t] * inv;
                    ssum[t] += sm;
                    wx[t] = fmaf(sm, f.x, wx[t]);
                    wy[t] = fmaf(sm, f.y, wy[t]);
                }
            }
        }
    }

    // ---- CV update (all 10 modes), r2 butterfly ----
    float r2[M_MODES];
    #pragma unroll
    for (int t = 0; t < M_MODES; ++t) {
        const float am = amount[cls * M_MODES + t];
        float w = ssum[t] / (ssum[t] + am);
        if (!(w == w)) w = 0.0f;
        const float dn = (ssum[t] == 0.0f) ? 1.0f : ssum[t];
        float ax = ao[t].x * (1.0f - w) + (wx[t] / dn) * w;
        float ay = ao[t].y * (1.0f - w) + (wy[t] / dn) * w;
        ao[t].x = ax; ao[t].y = ay;
        r2[t] = ax * ax + ay * ay;
    }
    #pragma unroll
    for (int s = 1; s < 64; s <<= 1)
        #pragma unroll
        for (int t = 0; t < M_MODES; ++t) r2[t] += __shfl_xor(r2[t], s);

    // ---- write B tile: normalized fp16 prototypes, swizzled 4B writes ----
    // row r = wave*10+t, byte col = lane*4; slot j = lane>>2, off = (lane*4)&15
    #pragma unroll
    for (int t = 0; t < M_MODES; ++t) {
        const float R   = sqrtf(r2[t]);
        const float nrm = fmaxf(R, 1e-12f);
        const int   r   = wave * M_MODES + t;
        char* dst = smemB + SWZ(r, lane >> 2) + ((lane * 4) & 15);
        *(h16x2*)dst = (h16x2){(h16)(ao[t].x / nrm), (h16)(ao[t].y / nrm)};
    }

    // ---- kappa + cmc constants (lane t handles mode t; SoA in LDS) ----
    if (lane < M_MODES) {
        float myr2 = 0.f;
        #pragma unroll
        for (int t = 0; t < M_MODES; ++t) if (lane == t) myr2 = r2[t];
        const float R = sqrtf(myr2);
        float kappa = 128.0f * R / (1.0f - R * R);
        if (kappa > 1e5f || kappa < 0.0f) kappa = 1e5f;
        float k   = kappa;
        float swk = sqrtf(fmaf(k, k, 3969.0f));
        float i1  = 1.0f / (63.0f + swk);
        float i2  = 1.0f / swk;
        const int cmL = wave * M_MODES + lane;   // 0..79
        cmcs[0 * 80 + cmL] = 2.0f * k;
        cmcs[1 * 80 + cmL] = fmaf(k, k, 3970.0f);
        cmcs[2 * 80 + cmL] = swk;
        cmcs[3 * 80 + cmL] = 1.0f - 63.0f * i1 - 0.5f * i2;
        cmcs[4 * 80 + cmL] = 31.5f * i1 * i1 + 0.25f * i2 * i2;
        cmcs[5 * 80 + cmL] = -(21.0f * i1 * i1 * i1 + (1.0f / 6.0f) * i2 * i2 * i2);
    }
    __syncthreads();

    // ---- MFMA: 16 n-rows per wave x 80 cm ----
    const int lrow = lane & 15;
    const int lhi  = lane >> 4;

    f32x4 acc[5] = {};
    #pragma unroll
    for (int ks = 0; ks < 4; ++ks) {
        half8 a = *(const half8*)(smem + SWZ(wave * 16 + lrow, ks * 4 + lhi));
        #pragma unroll
        for (int t = 0; t < 5; ++t) {
            half8 b = *(const half8*)(smemB + SWZ(t * 16 + lrow, ks * 4 + lhi));
            acc[t] = __builtin_amdgcn_mfma_f32_16x16x32_f16(a, b, acc[t], 0, 0, 0);
        }
    }

    // ---- epilogue: rational vMF logit; constants from LDS (broadcast) ----
    #pragma unroll
    for (int t = 0; t < 5; ++t) {
        const int cmL = t * 16 + lrow;
        const float c2k = cmcs[0 * 80 + cmL];
        const float k2p = cmcs[1 * 80 + cmL];
        const float swk = cmcs[2 * 80 + cmL];
        const float c1  = cmcs[3 * 80 + cmL];
        const float c2  = cmcs[4 * 80 + cmL];
        const float c3  = cmcs[5 * 80 + cmL];
        #pragma unroll
        for (int r = 0; r < 4; ++r) {
            float s   = acc[t][r];
            float swn = sqrtf(fmaf(c2k, s, k2p));
            float num = fmaf(c2k, s, 1.0f);
            float D   = __fdividef(num, swn + swk);
            acc[t][r] = D * fmaf(D, fmaf(D, c3, c2), c1);
        }
    }

    // ---- single-pass mode-max via ls overlay ----
    __syncthreads();
    #pragma unroll
    for (int t = 0; t < 5; ++t)
        #pragma unroll
        for (int r = 0; r < 4; ++r)
            ls[(wave * 16 + lhi * 4 + r) * LSTR + t * 16 + lrow] = acc[t][r];
    __syncthreads();

    #pragma unroll
    for (int rep = 0; rep < 2; ++rep) {
        int id = rep * 512 + tid;
        int q  = id >> 3;
        int cl = id & 7;
        const float* row = ls + q * LSTR + cl * 10;
        float mx = row[0];
        #pragma unroll
        for (int j = 1; j < 10; ++j) mx = fmaxf(mx, row[j]);
        out[(nbase + q) * C_NUM + blockIdx.x * 8 + cl] = mx;
    }
}

extern "C" void kernel_launch(void* const* d_in, const int* in_sizes, int n_in,
                              void* d_out, int out_size, void* d_ws, size_t ws_size,
                              hipStream_t stream) {
    const float* feat    = (const float*)d_in[0];
    const float* ave_old = (const float*)d_in[1];
    const float* amount  = (const float*)d_in[2];
    const int*   labels  = (const int*)d_in[3];
    float* out = (float*)d_out;
    float* ws  = (float*)d_ws;

    h16* feat_h = (h16*)(ws + OFF_FEATH);

    feat_cvt<<<dim3(256), dim3(256), 0, stream>>>(feat, feat_h);

    k3_fused<<<dim3(125, 8), dim3(512), 0, stream>>>(
        feat_h, feat, ave_old, amount, labels, out);
}

// Round 14
// 100.093 us; speedup vs baseline: 1.2217x; 1.2217x over previous
//
#include <hip/hip_runtime.h>
#include <math.h>

#define C_NUM 1000
#define M_MODES 10
#define D_FEAT 128
#define N_BATCH 1024

typedef _Float16 h16;
typedef h16 h16x2 __attribute__((ext_vector_type(2)));
typedef h16 half8 __attribute__((ext_vector_type(8)));
typedef float f32x4 __attribute__((ext_vector_type(4)));

// ---------------- fully fused single kernel ---------------------------------
// grid (125, 2), 512 threads. Block x-tile = 80 cm = 8 whole classes.
// Wave w preps class blockIdx.x*8+w ONCE (norms, label scan via ballot,
// softmax/CV, kappa, cmc -> LDS), writing the fp16 B tile directly to LDS in
// PERMUTED row order p(cl,m) = (m>>1)*16 + (m&1)*8 + cl, so that MFMA fragment
// t, lane-col j holds class j&7, mode 2t+(j>>3). Mode-max then = 4 register
// fmax + one shfl_xor(8); no LDS transpose buffer at all.
// Then 4 y-tiles of 128 n-rows: stage A (fp32->fp16 inline), 20 MFMA,
// rational vMF logit, class-max, store. 2 barriers per y-tile.
// cmc SoA[q][p]: q=0..5 = { 2k, k*k+3970, sw_k, c1, c2, c3 };
// logit(s) = D*(c1 + D*(c2 + D*c3)), D = (2k*s+1)/(sw_new+sw_k).
#define SWZ(row, j) (((row) << 8) + ((((j) ^ ((row) & 15))) << 4))
__global__ __launch_bounds__(512, 2) void procom_fused(
    const float* __restrict__ feat,      // [1024][128]
    const float* __restrict__ ave_old,   // [1000][10][128]
    const float* __restrict__ amount,    // [10000]
    const int*   __restrict__ labels,    // [1024]
    float* __restrict__ out)             // [1024][1000]
{
    __shared__ __align__(16) char smem[128 * 256 + 80 * 256 + 6 * 80 * 4];
    char*  smemB = smem + 128 * 256;
    float* cmcs  = (float*)(smemB + 80 * 256);   // [6][80] SoA, indexed by p

    const int tid  = threadIdx.x;
    const int wave = tid >> 6;            // 0..7
    const int lane = tid & 63;
    const int cls  = blockIdx.x * 8 + wave;      // class this wave preps

    const float2* feat2 = (const float2*)feat;
    const float2* ave2  = (const float2*)ave_old;

    // ================= in-block prep (wave-local, no barriers) ==============
    float2 ao[M_MODES];
    #pragma unroll
    for (int t = 0; t < M_MODES; ++t) ao[t] = ave2[(cls * M_MODES + t) * 64 + lane];

    float an[M_MODES];
    #pragma unroll
    for (int t = 0; t < M_MODES; ++t) an[t] = ao[t].x * ao[t].x + ao[t].y * ao[t].y;
    #pragma unroll
    for (int s = 1; s < 64; s <<= 1)
        #pragma unroll
        for (int t = 0; t < M_MODES; ++t) an[t] += __shfl_xor(an[t], s);
    #pragma unroll
    for (int t = 0; t < M_MODES; ++t) an[t] = sqrtf(an[t]);

    float ssum[M_MODES], wx[M_MODES], wy[M_MODES];
    #pragma unroll
    for (int t = 0; t < M_MODES; ++t) { ssum[t] = 0.f; wx[t] = 0.f; wy[t] = 0.f; }

    const int4* lab4 = (const int4*)labels;
    #pragma unroll 1
    for (int k4 = 0; k4 < 4; ++k4) {
        int4 lv = lab4[lane + k4 * 64];
        #pragma unroll
        for (int j = 0; j < 4; ++j) {
            int lbl = (j == 0) ? lv.x : (j == 1) ? lv.y : (j == 2) ? lv.z : lv.w;
            unsigned long long mask = __ballot(lbl == cls);
            while (mask) {
                int lz = __ffsll((long long)mask) - 1;
                mask &= mask - 1;
                const int n = 4 * lz + 256 * k4 + j;
                float2 f = feat2[n * 64 + lane];
                float d[M_MODES], fn = f.x * f.x + f.y * f.y;
                #pragma unroll
                for (int t = 0; t < M_MODES; ++t)
                    d[t] = f.x * ao[t].x + f.y * ao[t].y;
                #pragma unroll
                for (int s = 1; s < 64; s <<= 1) {
                    fn += __shfl_xor(fn, s);
                    #pragma unroll
                    for (int t = 0; t < M_MODES; ++t) d[t] += __shfl_xor(d[t], s);
                }
                const float fnorm = sqrtf(fn);
                float sc[M_MODES], mxv = -INFINITY;
                #pragma unroll
                for (int t = 0; t < M_MODES; ++t) {
                    float den = fmaxf(fnorm * an[t], 1e-8f);
                    sc[t] = d[t] / den;
                    mxv = fmaxf(mxv, sc[t]);
                }
                float se = 0.f;
                #pragma unroll
                for (int t = 0; t < M_MODES; ++t) { sc[t] = __expf(sc[t] - mxv); se += sc[t]; }
                const float inv = 1.0f / se;
                #pragma unroll
                for (int t = 0; t < M_MODES; ++t) {
                    float sm = sc[t] * inv;
                    ssum[t] += sm;
                    wx[t] = fmaf(sm, f.x, wx[t]);
                    wy[t] = fmaf(sm, f.y, wy[t]);
                }
            }
        }
    }

    // CV update (all 10 modes) + fused r2 butterfly
    float r2[M_MODES];
    #pragma unroll
    for (int t = 0; t < M_MODES; ++t) {
        const float am = amount[cls * M_MODES + t];
        float w = ssum[t] / (ssum[t] + am);
        if (!(w == w)) w = 0.0f;
        const float dn = (ssum[t] == 0.0f) ? 1.0f : ssum[t];
        float ax = ao[t].x * (1.0f - w) + (wx[t] / dn) * w;
        float ay = ao[t].y * (1.0f - w) + (wy[t] / dn) * w;
        ao[t].x = ax; ao[t].y = ay;
        r2[t] = ax * ax + ay * ay;
    }
    #pragma unroll
    for (int s = 1; s < 64; s <<= 1)
        #pragma unroll
        for (int t = 0; t < M_MODES; ++t) r2[t] += __shfl_xor(r2[t], s);

    // B tile -> LDS at permuted row p(cls_local=wave, mode=t)
    #pragma unroll
    for (int t = 0; t < M_MODES; ++t) {
        const float R   = sqrtf(r2[t]);
        const float nrm = fmaxf(R, 1e-12f);
        const int   p   = ((t >> 1) << 4) + ((t & 1) << 3) + wave;
        char* dst = smemB + SWZ(p, lane >> 2) + ((lane * 4) & 15);
        *(h16x2*)dst = (h16x2){(h16)(ao[t].x / nrm), (h16)(ao[t].y / nrm)};
    }

    // kappa + cmc constants at permuted index p (lane t handles mode t)
    if (lane < M_MODES) {
        float myr2 = 0.f;
        #pragma unroll
        for (int t = 0; t < M_MODES; ++t) if (lane == t) myr2 = r2[t];
        const float R = sqrtf(myr2);
        float kappa = 128.0f * R / (1.0f - R * R);
        if (kappa > 1e5f || kappa < 0.0f) kappa = 1e5f;
        float k   = kappa;
        float swk = sqrtf(fmaf(k, k, 3969.0f));
        float i1  = 1.0f / (63.0f + swk);
        float i2  = 1.0f / swk;
        const int p = ((lane >> 1) << 4) + ((lane & 1) << 3) + wave;
        cmcs[0 * 80 + p] = 2.0f * k;
        cmcs[1 * 80 + p] = fmaf(k, k, 3970.0f);
        cmcs[2 * 80 + p] = swk;
        cmcs[3 * 80 + p] = 1.0f - 63.0f * i1 - 0.5f * i2;
        cmcs[4 * 80 + p] = 31.5f * i1 * i1 + 0.25f * i2 * i2;
        cmcs[5 * 80 + p] = -(21.0f * i1 * i1 * i1 + (1.0f / 6.0f) * i2 * i2 * i2);
    }

    // ================= GEMM + epilogue over 4 y-tiles =======================
    const int lrow = lane & 15;
    const int lhi  = lane >> 4;

    for (int yi = 0; yi < 4; ++yi) {
        const int nbase = (blockIdx.y * 4 + yi) * 128;
        const f32x4* fs = (const f32x4*)(feat + nbase * D_FEAT);

        // stage A: fp32 -> fp16 inline, swizzled 16B slots
        #pragma unroll
        for (int i = 0; i < 4; ++i) {
            int e = tid + i * 512;            // 0..2047
            int r = e >> 4, j = e & 15;
            f32x4 lo = fs[e * 2], hi = fs[e * 2 + 1];
            half8 hv;
            hv[0] = (h16)lo[0]; hv[1] = (h16)lo[1]; hv[2] = (h16)lo[2]; hv[3] = (h16)lo[3];
            hv[4] = (h16)hi[0]; hv[5] = (h16)hi[1]; hv[6] = (h16)hi[2]; hv[7] = (h16)hi[3];
            *(half8*)(smem + SWZ(r, j)) = hv;
        }
        __syncthreads();   // A staged; (iter 0: also B/cmc from prep)

        f32x4 acc[5] = {};
        #pragma unroll
        for (int ks = 0; ks < 4; ++ks) {
            half8 a = *(const half8*)(smem + SWZ(wave * 16 + lrow, ks * 4 + lhi));
            #pragma unroll
            for (int t = 0; t < 5; ++t) {
                half8 b = *(const half8*)(smemB + SWZ(t * 16 + lrow, ks * 4 + lhi));
                acc[t] = __builtin_amdgcn_mfma_f32_16x16x32_f16(a, b, acc[t], 0, 0, 0);
            }
        }

        // epilogue: rational logit + in-register class-max
        float mx[4] = { -INFINITY, -INFINITY, -INFINITY, -INFINITY };
        #pragma unroll
        for (int t = 0; t < 5; ++t) {
            const int p = t * 16 + lrow;
            const float c2k = cmcs[0 * 80 + p];
            const float k2p = cmcs[1 * 80 + p];
            const float swk = cmcs[2 * 80 + p];
            const float c1  = cmcs[3 * 80 + p];
            const float c2  = cmcs[4 * 80 + p];
            const float c3  = cmcs[5 * 80 + p];
            #pragma unroll
            for (int r = 0; r < 4; ++r) {
                float s   = acc[t][r];
                float swn = sqrtf(fmaf(c2k, s, k2p));
                float D   = __fdividef(fmaf(c2k, s, 1.0f), swn + swk);
                float lg  = D * fmaf(D, fmaf(D, c3, c2), c1);
                mx[r] = fmaxf(mx[r], lg);
            }
        }
        // combine even/odd mode halves: lanes j and j^8 hold the same class
        #pragma unroll
        for (int r = 0; r < 4; ++r) mx[r] = fmaxf(mx[r], __shfl_xor(mx[r], 8));

        if (lrow < 8) {
            #pragma unroll
            for (int r = 0; r < 4; ++r)
                out[(nbase + wave * 16 + lhi * 4 + r) * C_NUM
                    + blockIdx.x * 8 + lrow] = mx[r];
        }
        __syncthreads();   // MFMA A-reads done before next stage overwrites A
    }
}

extern "C" void kernel_launch(void* const* d_in, const int* in_sizes, int n_in,
                              void* d_out, int out_size, void* d_ws, size_t ws_size,
                              hipStream_t stream) {
    const float* feat    = (const float*)d_in[0];
    const float* ave_old = (const float*)d_in[1];
    const float* amount  = (const float*)d_in[2];
    const int*   labels  = (const int*)d_in[3];
    float* out = (float*)d_out;

    // single dispatch; d_ws unused
    procom_fused<<<dim3(125, 2), dim3(512), 0, stream>>>(
        feat, ave_old, amount, labels, out);
}

// Round 15
// 90.919 us; speedup vs baseline: 1.3450x; 1.1009x over previous
//
#include <hip/hip_runtime.h>
#include <math.h>

#define C_NUM 1000
#define M_MODES 10
#define CMTOT (C_NUM * M_MODES)   // 10000
#define D_FEAT 128
#define N_BATCH 1024

typedef _Float16 h16;
typedef h16 h16x2 __attribute__((ext_vector_type(2)));
typedef h16 half8 __attribute__((ext_vector_type(8)));
typedef float f32x4 __attribute__((ext_vector_type(4)));

// ---- workspace layout (float units) ----
#define OFF_FEATH  0              // h16[1024*128]  = 65536 floats
#define OFF_AVEH   65536          // h16[10000*128] = 640000 floats
#define OFF_CMC    705536         // float[10000*8] per-cm epilogue constants

// ---------------- K2': fused prep (block = one class) ------------------------
// (byte-identical to round 10's k2_fused — best measured prep at 12.3 us)
__global__ __launch_bounds__(256) void k2_fused(
    const float* __restrict__ feat,      // [1024][128]
    const float* __restrict__ ave_old,   // [1000][10][128]
    const float* __restrict__ amount,    // [10000]
    const int*   __restrict__ labels,    // [1024]
    h16*   __restrict__ feat_h,          // [1024][128]
    h16*   __restrict__ ave_h,           // [10000][128]
    float* __restrict__ cmc)             // [10000][8]
{
    const int c    = blockIdx.x;         // class 0..999
    const int tid  = threadIdx.x;
    const int wave = tid >> 6;
    const int lane = tid & 63;

    __shared__ int   s_cnt;
    __shared__ int   s_list[N_BATCH];        // 4 KB
    __shared__ float s_an[M_MODES];          // ||ave_old[c,m]||
    __shared__ float s_soft[N_BATCH * 10 / 4]; // cap 256 samples/class (10 KB)

    const float2* feat2 = (const float2*)feat;
    const float2* ave2  = (const float2*)ave_old;

    // feat -> fp16 (independent side task)
    if (c < 256) {
        const int n = c * 4 + wave;
        float2 f = feat2[n * 64 + lane];
        ((h16x2*)(feat_h + n * D_FEAT))[lane] = (h16x2){(h16)f.x, (h16)f.y};
    }

    if (tid == 0) s_cnt = 0;
    __syncthreads();

    // phase A: find my samples
    for (int n = tid; n < N_BATCH; n += 256)
        if (labels[n] == c) { int p = atomicAdd(&s_cnt, 1); s_list[p] = n; }

    // phase B: prototype norms
    #pragma unroll
    for (int m = wave; m < M_MODES; m += 4) {
        float2 a = ave2[(c * M_MODES + m) * 64 + lane];
        float an = a.x * a.x + a.y * a.y;
        #pragma unroll
        for (int s = 1; s < 64; s <<= 1) an += __shfl_xor(an, s);
        if (lane == 0) s_an[m] = sqrtf(an);
    }
    __syncthreads();

    const int nc = s_cnt < 256 ? s_cnt : 256;

    // phase C: soft assignment for my samples (one wave per sample)
    for (int i = wave; i < nc; i += 4) {
        const int n = s_list[i];
        float2 f = feat2[n * 64 + lane];
        float fn = f.x * f.x + f.y * f.y;
        float d[M_MODES];
        #pragma unroll
        for (int m = 0; m < M_MODES; ++m) {
            float2 a = ave2[(c * M_MODES + m) * 64 + lane];
            d[m] = f.x * a.x + f.y * a.y;
        }
        #pragma unroll
        for (int s = 1; s < 64; s <<= 1) {
            fn += __shfl_xor(fn, s);
            #pragma unroll
            for (int m = 0; m < M_MODES; ++m) d[m] += __shfl_xor(d[m], s);
        }
        const float fnorm = sqrtf(fn);
        float sc[M_MODES], mx = -INFINITY;
        #pragma unroll
        for (int m = 0; m < M_MODES; ++m) {
            float den = fmaxf(fnorm * s_an[m], 1e-8f);
            sc[m] = d[m] / den;
            mx = fmaxf(mx, sc[m]);
        }
        float se = 0.f;
        #pragma unroll
        for (int m = 0; m < M_MODES; ++m) { sc[m] = __expf(sc[m] - mx); se += sc[m]; }
        const float inv = 1.0f / se;
        if (lane == 0) {
            #pragma unroll
            for (int m = 0; m < M_MODES; ++m) s_soft[i * M_MODES + m] = sc[m] * inv;
        }
    }
    __syncthreads();

    // phase D: per-mode CV update + kappa + cmc (one wave per mode, strided)
    for (int m = wave; m < M_MODES; m += 4) {
        const int wid = c * M_MODES + m;
        float ssum = 0.f, wx = 0.f, wy = 0.f;
        for (int i = 0; i < nc; ++i) {
            float s  = s_soft[i * M_MODES + m];
            float2 f = feat2[s_list[i] * 64 + lane];
            ssum += s;
            wx = fmaf(s, f.x, wx);
            wy = fmaf(s, f.y, wy);
        }
        const float am = amount[wid];
        float w = ssum / (ssum + am);
        if (!(w == w)) w = 0.0f;
        const float dn = (ssum == 0.0f) ? 1.0f : ssum;

        float2 ao = ave2[wid * 64 + lane];
        float ax = ao.x * (1.0f - w) + (wx / dn) * w;
        float ay = ao.y * (1.0f - w) + (wy / dn) * w;

        float r2 = ax * ax + ay * ay;
        #pragma unroll
        for (int s2 = 1; s2 < 64; s2 <<= 1) r2 += __shfl_xor(r2, s2);
        const float R = sqrtf(r2);

        float kappa = 128.0f * R / (1.0f - R * R);
        if (kappa > 1e5f || kappa < 0.0f) kappa = 1e5f;

        const float nrm = fmaxf(R, 1e-12f);
        ((h16x2*)(ave_h + wid * D_FEAT))[lane] = (h16x2){(h16)(ax / nrm), (h16)(ay / nrm)};

        if (lane == 0) {
            float k   = kappa;
            float swk = sqrtf(fmaf(k, k, 3969.0f));
            float i1  = 1.0f / (63.0f + swk);
            float i2  = 1.0f / swk;
            float c1  = 1.0f - 63.0f * i1 - 0.5f * i2;
            float c2  = 31.5f * i1 * i1 + 0.25f * i2 * i2;
            float c3  = -(21.0f * i1 * i1 * i1 + (1.0f / 6.0f) * i2 * i2 * i2);
            float4* p = (float4*)(cmc + wid * 8);
            p[0] = make_float4(2.0f * k, fmaf(k, k, 3970.0f), swk, c1);
            p[1] = make_float4(c2, c3, 0.0f, 0.0f);
        }
    }
}

// ---------------- K3: f16 MFMA sims-GEMM + rational logit + register max -----
// R10 structure (512 thr, 128n x 80cm tile) + R14's hardware-verified permuted
// B layout: LDS row p(cl,m) = (m>>1)*16 + (m&1)*8 + cl. MFMA fragment t,
// lane-col j then holds class j&7, mode 2t+(j>>3) -> mode-max is 4 register
// fmax + one shfl_xor(8). No ls transpose buffer; ONE barrier total.
#define SWZ(row, j) (((row) << 8) + ((((j) ^ ((row) & 15))) << 4))
__global__ __launch_bounds__(512) void k3_logits(
    const h16*   __restrict__ feat_h,    // [1024][128]
    const h16*   __restrict__ ave_h,     // [10000][128]
    const float* __restrict__ cmc,       // [10000][8]
    float* __restrict__ out)             // [1024][1000]
{
    __shared__ __align__(16) char smem[128 * 256 + 80 * 256];  // 52 KB
    char* smemB = smem + 128 * 256;

    const int tid    = threadIdx.x;
    const int cmbase = blockIdx.x * 80;   // 125 x-tiles (8 whole classes)
    const int nbase  = blockIdx.y * 128;  // 8 y-tiles

    // stage A: 128 rows x 16 float4, swizzled
    {
        const float4* src = (const float4*)(feat_h + nbase * D_FEAT);
        #pragma unroll
        for (int i = 0; i < 4; ++i) {
            int e = tid + i * 512;
            int r = e >> 4, j = e & 15;
            *(float4*)(smem + SWZ(r, j)) = src[e];
        }
    }
    // stage B: 80 rows, PERMUTED row placement p(cl,m)
    for (int e = tid; e < 1280; e += 512) {
        int r = e >> 4, j = e & 15;          // r = cl*10 + m (source order)
        int cl = r / 10;                     // magic-mul, r < 80
        int m  = r - cl * 10;
        int p  = ((m >> 1) << 4) + ((m & 1) << 3) + cl;
        *(float4*)(smemB + SWZ(p, j)) = ((const float4*)(ave_h + cmbase * D_FEAT))[e];
    }
    __syncthreads();                          // the only barrier

    const int wave = tid >> 6;    // 0..7 -> n-rows wave*16..wave*16+15
    const int lane = tid & 63;
    const int lrow = lane & 15;
    const int lhi  = lane >> 4;

    f32x4 acc[5] = {};
    #pragma unroll
    for (int ks = 0; ks < 4; ++ks) {
        half8 a = *(const half8*)(smem + SWZ(wave * 16 + lrow, ks * 4 + lhi));
        #pragma unroll
        for (int t = 0; t < 5; ++t) {
            half8 b = *(const half8*)(smemB + SWZ(t * 16 + lrow, ks * 4 + lhi));
            acc[t] = __builtin_amdgcn_mfma_f32_16x16x32_f16(a, b, acc[t], 0, 0, 0);
        }
    }

    // epilogue: rational vMF logit + in-register class-max over modes
    // fragment t, lane-col lrow: class = lrow&7, mode = 2t + (lrow>>3)
    float mx[4] = { -INFINITY, -INFINITY, -INFINITY, -INFINITY };
    #pragma unroll
    for (int t = 0; t < 5; ++t) {
        const int cm = (cmbase + (lrow & 7) * 10) + 2 * t + (lrow >> 3);
        float4 p0 = ((const float4*)(cmc + cm * 8))[0];  // 2k, k^2+3970, swk, c1
        float4 p1 = ((const float4*)(cmc + cm * 8))[1];  // c2, c3
        #pragma unroll
        for (int r = 0; r < 4; ++r) {
            float s   = acc[t][r];
            float swn = sqrtf(fmaf(p0.x, s, p0.y));
            float D   = __fdividef(fmaf(p0.x, s, 1.0f), swn + p0.z);
            float lg  = D * fmaf(D, fmaf(D, p1.y, p1.x), p0.w);
            mx[r] = fmaxf(mx[r], lg);
        }
    }
    // combine even/odd mode halves: lanes j and j^8 share a class
    #pragma unroll
    for (int r = 0; r < 4; ++r) mx[r] = fmaxf(mx[r], __shfl_xor(mx[r], 8));

    if (lrow < 8) {
        #pragma unroll
        for (int r = 0; r < 4; ++r)
            out[(nbase + wave * 16 + lhi * 4 + r) * C_NUM
                + blockIdx.x * 8 + lrow] = mx[r];
    }
}

extern "C" void kernel_launch(void* const* d_in, const int* in_sizes, int n_in,
                              void* d_out, int out_size, void* d_ws, size_t ws_size,
                              hipStream_t stream) {
    const float* feat    = (const float*)d_in[0];
    const float* ave_old = (const float*)d_in[1];
    const float* amount  = (const float*)d_in[2];
    const int*   labels  = (const int*)d_in[3];
    float* out = (float*)d_out;
    float* ws  = (float*)d_ws;

    h16*   feat_h = (h16*)(ws + OFF_FEATH);
    h16*   ave_h  = (h16*)(ws + OFF_AVEH);
    float* cmc    = ws + OFF_CMC;

    k2_fused<<<dim3(C_NUM), dim3(256), 0, stream>>>(
        feat, ave_old, amount, labels, feat_h, ave_h, cmc);

    k3_logits<<<dim3(125, 8), dim3(512), 0, stream>>>(
        feat_h, ave_h, cmc, out);
}